// Round 17
// baseline (34.751 us; speedup 1.0000x reference)
//
#include <hip/hip_runtime.h>
#include <hip/hip_bf16.h>
#include <cstdint>
#include <cstddef>

// Problem dims (fixed by the reference: B=4, C=256, H=W=64)
#define C_    256
#define C8_   32
#define NPIX  4096
#define BATCH 4
#define OUT_ELEMS (BATCH * C_ * NPIX)   // out [4,256,64,64]; then attention [4096][4096]

typedef short bf16x8 __attribute__((ext_vector_type(8)));   // 8 bf16 in 4 VGPRs
typedef float f32x4  __attribute__((ext_vector_type(4)));
typedef unsigned uint32x2 __attribute__((ext_vector_type(2)));

#define LOG2E 1.44269504088896340736f

// k_attn6 LDS p-staging: per wave [16 rows][520 bf16] (512 data + 8 pad).
// 8*16*520*2B = 130 KB -> 1 block/CU (fine: only 256 attn blocks at gamma==0).
#define PROW 520

static __device__ __forceinline__ unsigned short f2bf(float f) {
    union { float f; unsigned u; } v; v.f = f;
    unsigned r = v.u + 0x7fff + ((v.u >> 16) & 1);   // RNE
    return (unsigned short)(r >> 16);
}

// pack two f32 -> two bf16 (TRUNCATE) in one v_perm: low half = p0, high = p1
static __device__ __forceinline__ unsigned pack_bf2(float p0, float p1) {
    union { float f; unsigned u; } a, b; a.f = p0; b.f = p1;
    return __builtin_amdgcn_perm(b.u, a.u, 0x07060302u);
}
static __device__ __forceinline__ float unpk_lo(unsigned u) {
    union { unsigned u; float f; } v; v.u = u << 16; return v.f;
}
static __device__ __forceinline__ float unpk_hi(unsigned u) {
    union { unsigned u; float f; } v; v.u = u & 0xffff0000u; return v.f;
}

static __device__ __forceinline__ f32x4 mfma16(bf16x8 a, bf16x8 b, f32x4 c) {
    return __builtin_amdgcn_mfma_f32_16x16x32_bf16(a, b, c, 0, 0, 0);
}

// ---------------------------------------------------------------------------
// K1 "k_pre": [0,2048)    qk projection (R9-proven path) + folded v (gamma!=0)
//             [2048,4096) out = x copy (overlaps the serial qk phase)
// qk blocks take the lowest ids -> dispatched first (critical path).
//   qT,kT: bf16 [B][N][32] (c contiguous). q PRESCALED by log2(e).
//   vB   : bf16 [B][C][N]
// ---------------------------------------------------------------------------
__global__ __launch_bounds__(256) void k_pre(
    const float* __restrict__ x,
    const float* __restrict__ Wq, const float* __restrict__ bq,
    const float* __restrict__ Wk, const float* __restrict__ bk,
    const float* __restrict__ Wv, const float* __restrict__ bv,
    const float* __restrict__ gamma,
    float* __restrict__ out,
    unsigned short* __restrict__ qT,
    unsigned short* __restrict__ kT,
    unsigned short* __restrict__ vB)
{
    __shared__ float xs[256][64];     // 64 KB x-tile
    __shared__ float pred[4][8][64];  // 8 KB cross-wave partials

    const int bid = blockIdx.x;
    const float gval = gamma[0];

    if (bid >= 2048) {                      // ---- copy role ----
        const size_t base = (size_t)(bid - 2048) * 256 + threadIdx.x;  // f32x4
        const f32x4* src = (const f32x4*)x;
        f32x4* dst = (f32x4*)out;
        f32x4 a = src[base];
        f32x4 b = src[base + 524288];
        __builtin_nontemporal_store(a, dst + base);
        __builtin_nontemporal_store(b, dst + base + 524288);
        return;
    }

    // ---- qk projection role ----
    const int b   = bid >> 9;               // 512 blocks per batch
    if (gval == 0.0f && b > 0) return;      // attention only observed at b==0
    const int sub  = bid & 511;
    const int og8  = sub >> 6;              // 0..7: 0-3 = q, 4-7 = k (uniform)
    const int n0   = (sub & 63) * 64;
    const bool is_q = (og8 < 4);
    const int obase = (og8 & 3) * 8;        // 8 qk outputs per block

    // stage x-tile [256 c][64 n]: 16 independent f32x4 loads per thread
    const int tl = threadIdx.x & 15;        // col group (4 floats)
    const int tr = threadIdx.x >> 4;        // row within pass (0..15)
    const float* xb = x + (size_t)b * C_ * NPIX + n0;
    f32x4 v[16];
#pragma unroll
    for (int p = 0; p < 16; ++p)
        v[p] = *(const f32x4*)(xb + (size_t)(p * 16 + tr) * NPIX + tl * 4);
#pragma unroll
    for (int p = 0; p < 16; ++p)
        *(f32x4*)&xs[p * 16 + tr][tl * 4] = v[p];
    __syncthreads();

    // each wave reduces its c-chunk of 64 for 8 outputs x 64 pixels
    const int wv = __builtin_amdgcn_readfirstlane(threadIdx.x >> 6); // 0..3
    const int ln = threadIdx.x & 63;        // pixel
    const float* Wb = (is_q ? Wq : Wk);     // uniform (blockIdx-derived)
    float acc[8] = {0.f, 0.f, 0.f, 0.f, 0.f, 0.f, 0.f, 0.f};
#pragma unroll 8
    for (int cc = 0; cc < 64; ++cc) {
        const int c = wv * 64 + cc;         // wave-uniform -> W via s_load
        const float xv = xs[c][ln];
#pragma unroll
        for (int o = 0; o < 8; ++o)
            acc[o] = fmaf(Wb[(size_t)(obase + o) * C_ + c], xv, acc[o]);
    }
#pragma unroll
    for (int o = 0; o < 8; ++o) pred[wv][o][ln] = acc[o];
    __syncthreads();

    // reduce 4 partials + bias, convert, store (thread t -> 2 outputs)
    const int o1 = threadIdx.x >> 6;        // 0..3
    const int n  = threadIdx.x & 63;
#pragma unroll
    for (int k = 0; k < 2; ++k) {
        const int ol = o1 + k * 4;
        const int oa = obase + ol;
        float s = pred[0][ol][n] + pred[1][ol][n] +
                  pred[2][ol][n] + pred[3][ol][n];
        if (is_q) {
            s = (s + bq[oa]) * LOG2E;
            qT[((size_t)b * NPIX + n0 + n) * C8_ + oa] = f2bf(s);
        } else {
            s = s + bk[oa];
            kT[((size_t)b * NPIX + n0 + n) * C8_ + oa] = f2bf(s);
        }
    }

    // ---- folded v projection (gamma != 0 only): 32 outputs in 4 chunks ----
    if (gval != 0.0f) {
        for (int ch = 0; ch < 4; ++ch) {
            const int vb0 = og8 * 32 + ch * 8;
            float vacc[8] = {0.f, 0.f, 0.f, 0.f, 0.f, 0.f, 0.f, 0.f};
#pragma unroll 8
            for (int cc = 0; cc < 64; ++cc) {
                const int c = wv * 64 + cc;
                const float xv = xs[c][ln];
#pragma unroll
                for (int o = 0; o < 8; ++o)
                    vacc[o] = fmaf(Wv[(size_t)(vb0 + o) * C_ + c], xv, vacc[o]);
            }
            __syncthreads();    // pred free from previous use
#pragma unroll
            for (int o = 0; o < 8; ++o) pred[wv][o][ln] = vacc[o];
            __syncthreads();
#pragma unroll
            for (int k = 0; k < 2; ++k) {
                const int ol = o1 + k * 4;
                const int oa = vb0 + ol;
                float s = pred[0][ol][n] + pred[1][ol][n] +
                          pred[2][ol][n] + pred[3][ol][n] + bv[oa];
                vB[((size_t)b * C_ + oa) * NPIX + n0 + n] = f2bf(s);
            }
        }
    }
}

// ---------------------------------------------------------------------------
// K2 "k_attn6": grid (256,4); b>0 && gamma==0 -> immediate return.
// Block = 16 query rows, 512 threads = 8 waves; wave w owns j in [w*512,+512).
// Single-pass energy -> exp2f -> packed bf16 ds_write into full 130 KB pbuf;
// one barrier; 1KB-contiguous nt f32x4 wave-stores. (R14's inline-asm
// v_exp_f32 produced NaN — TRANS-pipe wait-state hazard invisible to the
// compiler through the asm blob; exp2f lowers to v_exp_f32 anyway. Reverted.)
// No max subtraction (energy*log2e <= ~40; softmax(S)==softmax(S-m) exactly).
// Lane layout (m89-verified D): j = jw + s*16 + lg*4 + r, i = i0 + li.
// ---------------------------------------------------------------------------
__global__ __launch_bounds__(512) void k_attn6(
    const float* __restrict__ x,
    const unsigned short* __restrict__ qT,
    const unsigned short* __restrict__ kT,
    const unsigned short* __restrict__ vB,
    const float* __restrict__ gamma,
    float* __restrict__ out,
    float* __restrict__ attn)
{
    const int b = blockIdx.y;
    const float g = gamma[0];
    if (g == 0.0f && b > 0) return;   // block-uniform

    const int i0   = blockIdx.x * 16;
    const int t    = threadIdx.x;
    const int lane = t & 63;
    const int wavei = __builtin_amdgcn_readfirstlane(t >> 6);  // 0..7
    const int li   = lane & 15;
    const int lg   = lane >> 4;       // 0..3

    __shared__ unsigned short pbuf[8 * 16 * PROW];   // 130 KB p staging (bf16)
    __shared__ float red[8][16];

    const unsigned short* qTb = qT + (size_t)b * NPIX * C8_;
    const unsigned short* kTb = kT + (size_t)b * NPIX * C8_;

    // B fragment (Q, prescaled by log2e): rows i0+li, k-elems lg*8..+7
    bf16x8 qf = *(const bf16x8*)(qTb + (size_t)(i0 + li) * C8_ + lg * 8);

    const int jw = wavei * 512;
    unsigned short* prow = pbuf + (size_t)(wavei * 16 + li) * PROW;

    // one pass: energy -> exp2 -> packed bf16 into LDS + f32 row-sum
    float ssum = 0.f;
#pragma unroll
    for (int s = 0; s < 32; ++s) {
        bf16x8 kf = *(const bf16x8*)(kTb + (size_t)(jw + s * 16 + li) * C8_ + lg * 8);
        f32x4 z = {0.f, 0.f, 0.f, 0.f};
        f32x4 e = mfma16(kf, qf, z);           // e = S * log2e
        float p0 = exp2f(e[0]);
        float p1 = exp2f(e[1]);
        float p2 = exp2f(e[2]);
        float p3 = exp2f(e[3]);
        ssum += (p0 + p1) + (p2 + p3);
        uint32x2 pk;
        pk.x = pack_bf2(p0, p1);
        pk.y = pack_bf2(p2, p3);
        *(uint32x2*)(prow + s * 16 + lg * 4) = pk;   // 8B ds_write_b64
    }

    // row sum: in-wave (across lg) then cross-wave via LDS
    ssum += __shfl_xor(ssum, 16, 64);
    ssum += __shfl_xor(ssum, 32, 64);
    if (lane < 16) red[wavei][lane] = ssum;
    __syncthreads();                   // also makes pbuf visible block-wide
    float l = 0.f;
#pragma unroll
    for (int w = 0; w < 8; ++w) l += red[w][li];
    const float inv = 1.0f / l;        // row i0+li (lanes 0..15 canonical)

    // attention_map write (batch 0): per row, two 1KB-contiguous nt wave-stores
    if (b == 0) {
#pragma unroll
        for (int r = 0; r < 16; ++r) {
            const float inv_r = __shfl(inv, r, 64);
            const unsigned short* rp = pbuf + (size_t)(wavei * 16 + r) * PROW;
            float* ap = attn + (size_t)(i0 + r) * NPIX + jw;
            uint32x2 u0 = *(const uint32x2*)(rp + lane * 4);         // cols [0,256)
            uint32x2 u1 = *(const uint32x2*)(rp + 256 + lane * 4);   // cols [256,512)
            f32x4 v0, v1;
            v0[0] = unpk_lo(u0.x) * inv_r; v0[1] = unpk_hi(u0.x) * inv_r;
            v0[2] = unpk_lo(u0.y) * inv_r; v0[3] = unpk_hi(u0.y) * inv_r;
            v1[0] = unpk_lo(u1.x) * inv_r; v1[1] = unpk_hi(u1.x) * inv_r;
            v1[2] = unpk_lo(u1.y) * inv_r; v1[3] = unpk_hi(u1.y) * inv_r;
            __builtin_nontemporal_store(v0, (f32x4*)(ap + lane * 4));
            __builtin_nontemporal_store(v1, (f32x4*)(ap + 256 + lane * 4));
        }
    }

    // general path (gamma != 0): PV + out = gamma*attnout + x
    if (g != 0.0f) {
        f32x4 o0 = {0.f, 0.f, 0.f, 0.f};
        f32x4 o1 = {0.f, 0.f, 0.f, 0.f};
        const unsigned short* vb = vB + (size_t)b * C_ * NPIX;
        for (int st = 0; st < 8; ++st) {
            const int jbase = st * 512;
#pragma unroll
            for (int ks = 0; ks < 16; ++ks) {
                bf16x8 af = *(const bf16x8*)(pbuf + (size_t)(st * 16 + li) * PROW +
                                             ks * 32 + lg * 8);      // A[i, j] unnorm
                const unsigned short* vp0 =
                    vb + (size_t)(wavei * 32 + li) * NPIX + jbase + ks * 32 + lg * 8;
                bf16x8 vf0 = *(const bf16x8*)vp0;               // B[j, c-tile0]
                o0 = mfma16(af, vf0, o0);
                bf16x8 vf1 = *(const bf16x8*)(vp0 + (size_t)16 * NPIX);  // c-tile1
                o1 = mfma16(af, vf1, o1);
            }
        }
        // D2[i, c]: lane -> c = c0 + li, i = i0 + lg*4 + r; scale by g*inv[i]
        const float* xbt = x + (size_t)b * C_ * NPIX;
        float* outb = out + (size_t)b * C_ * NPIX;
        f32x4 sc;
#pragma unroll
        for (int r = 0; r < 4; ++r) sc[r] = g * __shfl(inv, lg * 4 + r, 64);
        {
            int c = wavei * 32 + li;
            f32x4 xv = *(const f32x4*)(xbt + (size_t)c * NPIX + i0 + lg * 4);
            f32x4 r0 = o0 * sc + xv;
            *(f32x4*)(outb + (size_t)c * NPIX + i0 + lg * 4) = r0;
            c += 16;
            f32x4 xv1 = *(const f32x4*)(xbt + (size_t)c * NPIX + i0 + lg * 4);
            f32x4 r1 = o1 * sc + xv1;
            *(f32x4*)(outb + (size_t)c * NPIX + i0 + lg * 4) = r1;
        }
    }
}

extern "C" void kernel_launch(void* const* d_in, const int* in_sizes, int n_in,
                              void* d_out, int out_size, void* d_ws, size_t ws_size,
                              hipStream_t stream) {
    (void)in_sizes; (void)n_in; (void)out_size; (void)ws_size;
    const float* x     = (const float*)d_in[0];
    const float* Wq    = (const float*)d_in[1];
    const float* bq    = (const float*)d_in[2];
    const float* Wk    = (const float*)d_in[3];
    const float* bk    = (const float*)d_in[4];
    const float* Wv    = (const float*)d_in[5];
    const float* bv    = (const float*)d_in[6];
    const float* gamma = (const float*)d_in[7];

    float* out  = (float*)d_out;
    float* attn = out + OUT_ELEMS;

    unsigned short* qT = (unsigned short*)d_ws;                       // 1 MB
    unsigned short* kT = qT + (size_t)BATCH * NPIX * C8_;             // 1 MB
    unsigned short* vB = kT + (size_t)BATCH * NPIX * C8_;             // 8 MB (gamma!=0 only)

    k_pre<<<4096, 256, 0, stream>>>(x, Wq, bq, Wk, bk, Wv, bv, gamma,
                                    out, qT, kT, vB);

    dim3 g2(NPIX / 16, BATCH);
    k_attn6<<<g2, 512, 0, stream>>>(x, qT, kT, vB, gamma, out, attn);
}

// Round 18
// 33.021 us; speedup vs baseline: 1.0524x; 1.0524x over previous
//
#include <hip/hip_runtime.h>
#include <hip/hip_bf16.h>
#include <cstdint>
#include <cstddef>

// Problem dims (fixed by the reference: B=4, C=256, H=W=64)
#define C_    256
#define C8_   32
#define NPIX  4096
#define BATCH 4
#define OUT_ELEMS (BATCH * C_ * NPIX)   // out [4,256,64,64]; then attention [4096][4096]

typedef short bf16x8 __attribute__((ext_vector_type(8)));   // 8 bf16 in 4 VGPRs
typedef float f32x4  __attribute__((ext_vector_type(4)));
typedef unsigned uint32x2 __attribute__((ext_vector_type(2)));

#define LOG2E 1.44269504088896340736f

// LDS p-staging: per wave [16 rows][520 bf16] (512 data + 8 pad). 130 KB.
#define PROW 520

static __device__ __forceinline__ unsigned short f2bf(float f) {
    union { float f; unsigned u; } v; v.f = f;
    unsigned r = v.u + 0x7fff + ((v.u >> 16) & 1);   // RNE
    return (unsigned short)(r >> 16);
}

// pack two f32 -> two bf16 (TRUNCATE) in one v_perm: low half = p0, high = p1
static __device__ __forceinline__ unsigned pack_bf2(float p0, float p1) {
    union { float f; unsigned u; } a, b; a.f = p0; b.f = p1;
    return __builtin_amdgcn_perm(b.u, a.u, 0x07060302u);
}
static __device__ __forceinline__ float unpk_lo(unsigned u) {
    union { unsigned u; float f; } v; v.u = u << 16; return v.f;
}
static __device__ __forceinline__ float unpk_hi(unsigned u) {
    union { unsigned u; float f; } v; v.u = u & 0xffff0000u; return v.f;
}

static __device__ __forceinline__ f32x4 mfma16(bf16x8 a, bf16x8 b, f32x4 c) {
    return __builtin_amdgcn_mfma_f32_16x16x32_bf16(a, b, c, 0, 0, 0);
}

// ---------------------------------------------------------------------------
// K1 "k_pre": 2048 blocks, qk projection (R9-proven) + folded v (gamma!=0).
// Copy moved OUT (R11-proven better overlapped inside the attention dispatch).
//   qT,kT: bf16 [B][N][32] (c contiguous). q PRESCALED by log2(e).
//   vB   : bf16 [B][C][N]
// ---------------------------------------------------------------------------
__global__ __launch_bounds__(256) void k_pre(
    const float* __restrict__ x,
    const float* __restrict__ Wq, const float* __restrict__ bq,
    const float* __restrict__ Wk, const float* __restrict__ bk,
    const float* __restrict__ Wv, const float* __restrict__ bv,
    const float* __restrict__ gamma,
    unsigned short* __restrict__ qT,
    unsigned short* __restrict__ kT,
    unsigned short* __restrict__ vB)
{
    __shared__ float xs[256][64];     // 64 KB x-tile
    __shared__ float pred[4][8][64];  // 8 KB cross-wave partials

    const int bid = blockIdx.x;
    const float gval = gamma[0];

    const int b   = bid >> 9;               // 512 blocks per batch
    if (gval == 0.0f && b > 0) return;      // attention only observed at b==0
    const int sub  = bid & 511;
    const int og8  = sub >> 6;              // 0..7: 0-3 = q, 4-7 = k (uniform)
    const int n0   = (sub & 63) * 64;
    const bool is_q = (og8 < 4);
    const int obase = (og8 & 3) * 8;        // 8 qk outputs per block

    // stage x-tile [256 c][64 n]: 16 independent f32x4 loads per thread
    const int tl = threadIdx.x & 15;        // col group (4 floats)
    const int tr = threadIdx.x >> 4;        // row within pass (0..15)
    const float* xb = x + (size_t)b * C_ * NPIX + n0;
    f32x4 v[16];
#pragma unroll
    for (int p = 0; p < 16; ++p)
        v[p] = *(const f32x4*)(xb + (size_t)(p * 16 + tr) * NPIX + tl * 4);
#pragma unroll
    for (int p = 0; p < 16; ++p)
        *(f32x4*)&xs[p * 16 + tr][tl * 4] = v[p];
    __syncthreads();

    // each wave reduces its c-chunk of 64 for 8 outputs x 64 pixels
    const int wv = __builtin_amdgcn_readfirstlane(threadIdx.x >> 6); // 0..3
    const int ln = threadIdx.x & 63;        // pixel
    const float* Wb = (is_q ? Wq : Wk);     // uniform (blockIdx-derived)
    float acc[8] = {0.f, 0.f, 0.f, 0.f, 0.f, 0.f, 0.f, 0.f};
#pragma unroll 8
    for (int cc = 0; cc < 64; ++cc) {
        const int c = wv * 64 + cc;         // wave-uniform -> W via s_load
        const float xv = xs[c][ln];
#pragma unroll
        for (int o = 0; o < 8; ++o)
            acc[o] = fmaf(Wb[(size_t)(obase + o) * C_ + c], xv, acc[o]);
    }
#pragma unroll
    for (int o = 0; o < 8; ++o) pred[wv][o][ln] = acc[o];
    __syncthreads();

    // reduce 4 partials + bias, convert, store (thread t -> 2 outputs)
    const int o1 = threadIdx.x >> 6;        // 0..3
    const int n  = threadIdx.x & 63;
#pragma unroll
    for (int k = 0; k < 2; ++k) {
        const int ol = o1 + k * 4;
        const int oa = obase + ol;
        float s = pred[0][ol][n] + pred[1][ol][n] +
                  pred[2][ol][n] + pred[3][ol][n];
        if (is_q) {
            s = (s + bq[oa]) * LOG2E;
            qT[((size_t)b * NPIX + n0 + n) * C8_ + oa] = f2bf(s);
        } else {
            s = s + bk[oa];
            kT[((size_t)b * NPIX + n0 + n) * C8_ + oa] = f2bf(s);
        }
    }

    // ---- folded v projection (gamma != 0 only): 32 outputs in 4 chunks ----
    if (gval != 0.0f) {
        for (int ch = 0; ch < 4; ++ch) {
            const int vb0 = og8 * 32 + ch * 8;
            float vacc[8] = {0.f, 0.f, 0.f, 0.f, 0.f, 0.f, 0.f, 0.f};
#pragma unroll 8
            for (int cc = 0; cc < 64; ++cc) {
                const int c = wv * 64 + cc;
                const float xv = xs[c][ln];
#pragma unroll
                for (int o = 0; o < 8; ++o)
                    vacc[o] = fmaf(Wv[(size_t)(vb0 + o) * C_ + c], xv, vacc[o]);
            }
            __syncthreads();    // pred free from previous use
#pragma unroll
            for (int o = 0; o < 8; ++o) pred[wv][o][ln] = vacc[o];
            __syncthreads();
#pragma unroll
            for (int k = 0; k < 2; ++k) {
                const int ol = o1 + k * 4;
                const int oa = vb0 + ol;
                float s = pred[0][ol][n] + pred[1][ol][n] +
                          pred[2][ol][n] + pred[3][ol][n] + bv[oa];
                vB[((size_t)b * C_ + oa) * NPIX + n0 + n] = f2bf(s);
            }
        }
    }
}

// ---------------------------------------------------------------------------
// K2 "k_attn7": grid (256, 4).
//  gamma==0: b==0 -> attention; b>0 -> out=x copy slices (overlap, R11-proven).
//  gamma!=0: all blocks -> attention + PV + out epilogue (no copy needed).
// Energy phase identical to R17's proven attn6 (full 130 KB pbuf, exp2f).
// STORE PHASE CHANGED (R18 theory): wave w stores ROWS 2w,2w+1 COMPLETELY,
// walking j segments sequentially -> each row is one 16KB LINEAR stream.
// R17 walked 16 rows emitting 1KB chunks at 16KB stride (8 waves interleaved)
// = DRAM-page thrash; R4 evidence puts that store pattern at ~3 TB/s vs the
// harness fills' 6.7 TB/s dense-linear streams.
// Lane layout (m89-verified D): j = jw + s*16 + lg*4 + r, i = i0 + li.
// ---------------------------------------------------------------------------
__global__ __launch_bounds__(512) void k_attn7(
    const float* __restrict__ x,
    const unsigned short* __restrict__ qT,
    const unsigned short* __restrict__ kT,
    const unsigned short* __restrict__ vB,
    const float* __restrict__ gamma,
    float* __restrict__ out,
    float* __restrict__ attn)
{
    const int b = blockIdx.y;
    const float g = gamma[0];

    __shared__ unsigned short pbuf[8 * 16 * PROW];   // 130 KB p staging (bf16)
    __shared__ float red[8][16];

    if (g == 0.0f && b > 0) {               // ---- copy role (768 blocks) ----
        const int cb = (b - 1) * 256 + blockIdx.x;   // 0..767
        const size_t n4 = (size_t)OUT_ELEMS / 4;     // 1,048,576 f32x4
        const f32x4* src = (const f32x4*)x;
        f32x4* dst = (f32x4*)out;
        for (size_t i = (size_t)cb * 512 + threadIdx.x; i < n4;
             i += (size_t)768 * 512)
            __builtin_nontemporal_store(src[i], dst + i);
        return;
    }

    const int i0   = blockIdx.x * 16;
    const int t    = threadIdx.x;
    const int lane = t & 63;
    const int wavei = __builtin_amdgcn_readfirstlane(t >> 6);  // 0..7
    const int li   = lane & 15;
    const int lg   = lane >> 4;       // 0..3

    const unsigned short* qTb = qT + (size_t)b * NPIX * C8_;
    const unsigned short* kTb = kT + (size_t)b * NPIX * C8_;

    // B fragment (Q, prescaled by log2e): rows i0+li, k-elems lg*8..+7
    bf16x8 qf = *(const bf16x8*)(qTb + (size_t)(i0 + li) * C8_ + lg * 8);

    const int jw = wavei * 512;
    unsigned short* prow = pbuf + (size_t)(wavei * 16 + li) * PROW;

    // one pass: energy -> exp2 -> packed bf16 into LDS + f32 row-sum
    float ssum = 0.f;
#pragma unroll
    for (int s = 0; s < 32; ++s) {
        bf16x8 kf = *(const bf16x8*)(kTb + (size_t)(jw + s * 16 + li) * C8_ + lg * 8);
        f32x4 z = {0.f, 0.f, 0.f, 0.f};
        f32x4 e = mfma16(kf, qf, z);           // e = S * log2e
        float p0 = exp2f(e[0]);
        float p1 = exp2f(e[1]);
        float p2 = exp2f(e[2]);
        float p3 = exp2f(e[3]);
        ssum += (p0 + p1) + (p2 + p3);
        uint32x2 pk;
        pk.x = pack_bf2(p0, p1);
        pk.y = pack_bf2(p2, p3);
        *(uint32x2*)(prow + s * 16 + lg * 4) = pk;   // 8B ds_write_b64
    }

    // row sum: in-wave (across lg) then cross-wave via LDS
    ssum += __shfl_xor(ssum, 16, 64);
    ssum += __shfl_xor(ssum, 32, 64);
    if (lane < 16) red[wavei][lane] = ssum;
    __syncthreads();                   // also makes pbuf visible block-wide
    float l = 0.f;
#pragma unroll
    for (int w = 0; w < 8; ++w) l += red[w][li];
    const float inv = 1.0f / l;        // row i0+li (lanes 0..15 canonical)

    // attention_map write (batch 0): ROW-LINEAR. Wave w owns rows 2w, 2w+1;
    // j segments ascend -> 16KB sequential stream per row (DRAM-page friendly).
    if (b == 0) {
#pragma unroll
        for (int rr = 0; rr < 2; ++rr) {
            const int r = wavei * 2 + rr;
            const float inv_r = __shfl(inv, r, 64);
            float* rowp = attn + (size_t)(i0 + r) * NPIX;
#pragma unroll
            for (int seg = 0; seg < 8; ++seg) {
                const unsigned short* rp = pbuf + (size_t)(seg * 16 + r) * PROW;
                uint32x2 u0 = *(const uint32x2*)(rp + lane * 4);        // [0,256)
                uint32x2 u1 = *(const uint32x2*)(rp + 256 + lane * 4);  // [256,512)
                f32x4 v0, v1;
                v0[0] = unpk_lo(u0.x) * inv_r; v0[1] = unpk_hi(u0.x) * inv_r;
                v0[2] = unpk_lo(u0.y) * inv_r; v0[3] = unpk_hi(u0.y) * inv_r;
                v1[0] = unpk_lo(u1.x) * inv_r; v1[1] = unpk_hi(u1.x) * inv_r;
                v1[2] = unpk_lo(u1.y) * inv_r; v1[3] = unpk_hi(u1.y) * inv_r;
                __builtin_nontemporal_store(
                    v0, (f32x4*)(rowp + seg * 512 + lane * 4));
                __builtin_nontemporal_store(
                    v1, (f32x4*)(rowp + seg * 512 + 256 + lane * 4));
            }
        }
    }

    // general path (gamma != 0): PV + out = gamma*attnout + x
    if (g != 0.0f) {
        f32x4 o0 = {0.f, 0.f, 0.f, 0.f};
        f32x4 o1 = {0.f, 0.f, 0.f, 0.f};
        const unsigned short* vb = vB + (size_t)b * C_ * NPIX;
        for (int st = 0; st < 8; ++st) {
            const int jbase = st * 512;
#pragma unroll
            for (int ks = 0; ks < 16; ++ks) {
                bf16x8 af = *(const bf16x8*)(pbuf + (size_t)(st * 16 + li) * PROW +
                                             ks * 32 + lg * 8);      // A[i, j] unnorm
                const unsigned short* vp0 =
                    vb + (size_t)(wavei * 32 + li) * NPIX + jbase + ks * 32 + lg * 8;
                bf16x8 vf0 = *(const bf16x8*)vp0;               // B[j, c-tile0]
                o0 = mfma16(af, vf0, o0);
                bf16x8 vf1 = *(const bf16x8*)(vp0 + (size_t)16 * NPIX);  // c-tile1
                o1 = mfma16(af, vf1, o1);
            }
        }
        // D2[i, c]: lane -> c = c0 + li, i = i0 + lg*4 + r; scale by g*inv[i]
        const float* xbt = x + (size_t)b * C_ * NPIX;
        float* outb = out + (size_t)b * C_ * NPIX;
        f32x4 sc;
#pragma unroll
        for (int r = 0; r < 4; ++r) sc[r] = g * __shfl(inv, lg * 4 + r, 64);
        {
            int c = wavei * 32 + li;
            f32x4 xv = *(const f32x4*)(xbt + (size_t)c * NPIX + i0 + lg * 4);
            f32x4 r0 = o0 * sc + xv;
            *(f32x4*)(outb + (size_t)c * NPIX + i0 + lg * 4) = r0;
            c += 16;
            f32x4 xv1 = *(const f32x4*)(xbt + (size_t)c * NPIX + i0 + lg * 4);
            f32x4 r1 = o1 * sc + xv1;
            *(f32x4*)(outb + (size_t)c * NPIX + i0 + lg * 4) = r1;
        }
    }
}

extern "C" void kernel_launch(void* const* d_in, const int* in_sizes, int n_in,
                              void* d_out, int out_size, void* d_ws, size_t ws_size,
                              hipStream_t stream) {
    (void)in_sizes; (void)n_in; (void)out_size; (void)ws_size;
    const float* x     = (const float*)d_in[0];
    const float* Wq    = (const float*)d_in[1];
    const float* bq    = (const float*)d_in[2];
    const float* Wk    = (const float*)d_in[3];
    const float* bk    = (const float*)d_in[4];
    const float* Wv    = (const float*)d_in[5];
    const float* bv    = (const float*)d_in[6];
    const float* gamma = (const float*)d_in[7];

    float* out  = (float*)d_out;
    float* attn = out + OUT_ELEMS;

    unsigned short* qT = (unsigned short*)d_ws;                       // 1 MB
    unsigned short* kT = qT + (size_t)BATCH * NPIX * C8_;             // 1 MB
    unsigned short* vB = kT + (size_t)BATCH * NPIX * C8_;             // 8 MB (gamma!=0 only)

    k_pre<<<2048, 256, 0, stream>>>(x, Wq, bq, Wk, bk, Wv, bv, gamma,
                                    qT, kT, vB);

    dim3 g2(NPIX / 16, BATCH);
    k_attn7<<<g2, 512, 0, stream>>>(x, qT, kT, vB, gamma, out, attn);
}